// Round 1
// baseline (73.987 us; speedup 1.0000x reference)
//
#include <hip/hip_runtime.h>
#include <hip/hip_bf16.h>

#define N_CAND   500000
#define N_TILES  31250      // N_CAND / 16
#define EPS      1e-6f
#define INV_TEMP 10.0f
#define DT_STEP  0.1f

typedef __attribute__((ext_vector_type(8))) short  short8;
typedef __attribute__((ext_vector_type(4))) float  floatx4;

__device__ inline short f32_to_bf16_rne(float f) {
    unsigned u = __builtin_bit_cast(unsigned, f);
    u += 0x7FFFu + ((u >> 16) & 1u);
    return (short)(u >> 16);
}

// Load 8 consecutive floats at p, convert to bf16x8, accumulate sum of squares (f32).
__device__ inline void cvt8(const float* __restrict__ p, short8& b, float& ss) {
    floatx4 v0 = *(const floatx4*)p;
    floatx4 v1 = *(const floatx4*)(p + 4);
#pragma unroll
    for (int k = 0; k < 4; ++k) {
        ss = fmaf(v0[k], v0[k], ss);
        ss = fmaf(v1[k], v1[k], ss);
        b[k]     = f32_to_bf16_rne(v0[k]);
        b[k + 4] = f32_to_bf16_rne(v1[k]);
    }
}

// ---------------- Kernel 1: query flow step + q_pot + ws init ----------------
__global__ __launch_bounds__(256)
void query_kernel(const float* __restrict__ qz, const float* __restrict__ centers,
                  const float* __restrict__ mus, float* __restrict__ out,
                  float* __restrict__ ws) {
    int tid = threadIdx.x, wid = tid >> 6, lane = tid & 63;
    float q = qz[lane];                       // lane == dimension d
    float acc = 0.f, pot = 0.f;
    for (int j = wid * 32; j < wid * 32 + 32; ++j) {
        float diff = centers[j * 64 + lane] - q;
        float sq = diff * diff;
#pragma unroll
        for (int m = 1; m < 64; m <<= 1) sq += __shfl_xor(sq, m);
        float r = __builtin_amdgcn_sqrtf(fmaxf(sq, 1e-12f));
        float mu = mus[j];
        float w = mu * __builtin_amdgcn_rcpf(r * r * r + EPS);
        acc = fmaf(w, diff, acc);
        pot += mu * __builtin_amdgcn_rcpf(r + EPS);
    }
    __shared__ float accs[4][64];
    __shared__ float pots[4];
    accs[wid][lane] = acc;
    if (lane == 0) pots[wid] = pot;
    __syncthreads();
    if (tid < 64) {
        float a = accs[0][tid] + accs[1][tid] + accs[2][tid] + accs[3][tid];
        out[tid] = fmaf(DT_STEP, a, q);
    }
    if (tid == 0) {
        ws[0] = pots[0] + pots[1] + pots[2] + pots[3];   // q_pot
        ((unsigned*)ws)[1] = 0x7F800000u;                // min_s = +inf (bits)
        ws[2] = 0.f;                                     // sum accumulator
    }
}

// ---------------- Kernel 2: c_pot via bf16 MFMA, write s = |q_pot - pot|/T ----
__global__ __launch_bounds__(256)
void pot_kernel(const float* __restrict__ cand, const float* __restrict__ centers,
                const float* __restrict__ mus, const float* __restrict__ ws,
                float* __restrict__ s_out, unsigned* __restrict__ min_bits) {
    int tid = threadIdx.x, wid = tid >> 6, lane = tid & 63;
    int lr = lane & 15;       // A-row / B-col index within 16
    int lg = lane >> 4;       // k-chunk group 0..3

    // B fragments (centers as bf16), center norms (f32), mus — live in registers.
    short8 bfrag[8][2];
    float nc[8], mu[8];
#pragma unroll
    for (int ct = 0; ct < 8; ++ct) {
        int j = ct * 16 + lr;
        float ncp = 0.f;
#pragma unroll
        for (int ks = 0; ks < 2; ++ks)
            cvt8(centers + j * 64 + ks * 32 + lg * 8, bfrag[ct][ks], ncp);
        ncp += __shfl_xor(ncp, 16);
        ncp += __shfl_xor(ncp, 32);          // full ||center_j||^2 on all lanes
        nc[ct] = ncp;
        mu[ct] = mus[j];
    }
    float q_pot = ws[0];
    float local_min = 3.4e38f;

    int nwaves = gridDim.x * 4;
    for (int t = blockIdx.x * 4 + wid; t < N_TILES; t += nwaves) {
        int r0 = t * 16;
        short8 afrag[2];
        float nzp = 0.f;
#pragma unroll
        for (int ks = 0; ks < 2; ++ks)
            cvt8(cand + (size_t)(r0 + lr) * 64 + ks * 32 + lg * 8, afrag[ks], nzp);
        nzp += __shfl_xor(nzp, 16);
        nzp += __shfl_xor(nzp, 32);          // ||z_row||^2 for row lr, all chunk groups
        float nzv[4];
#pragma unroll
        for (int v = 0; v < 4; ++v) nzv[v] = __shfl(nzp, lg * 4 + v);

        float pot[4] = {0.f, 0.f, 0.f, 0.f};
#pragma unroll
        for (int ct = 0; ct < 8; ++ct) {
            floatx4 acc = {0.f, 0.f, 0.f, 0.f};
            acc = __builtin_amdgcn_mfma_f32_16x16x32_bf16(afrag[0], bfrag[ct][0], acc, 0, 0, 0);
            acc = __builtin_amdgcn_mfma_f32_16x16x32_bf16(afrag[1], bfrag[ct][1], acc, 0, 0, 0);
#pragma unroll
            for (int v = 0; v < 4; ++v) {
                // acc[v] = dot(row = lg*4+v, col = ct*16+lr)
                float d2 = fmaxf(nzv[v] + nc[ct] - 2.f * acc[v], 1e-12f);
                float d = __builtin_amdgcn_sqrtf(d2);
                pot[v] += mu[ct] * __builtin_amdgcn_rcpf(d + EPS);
            }
        }
        float s[4];
#pragma unroll
        for (int v = 0; v < 4; ++v) {
            float p = pot[v];
            p += __shfl_xor(p, 1);
            p += __shfl_xor(p, 2);
            p += __shfl_xor(p, 4);
            p += __shfl_xor(p, 8);           // sum over 16 col-lanes -> full pot
            s[v] = fabsf(q_pot - p) * INV_TEMP;
            local_min = fminf(local_min, s[v]);
        }
        if (lr == 0) {
            floatx4 sv = {s[0], s[1], s[2], s[3]};
            *(floatx4*)(s_out + r0 + lg * 4) = sv;   // rows r0+lg*4 .. +3
        }
    }
    // block-reduce min, one atomic per block (positive-float bits order as uints)
#pragma unroll
    for (int m = 1; m < 64; m <<= 1)
        local_min = fminf(local_min, __shfl_xor(local_min, m));
    __shared__ float red[4];
    if (lane == 0) red[wid] = local_min;
    __syncthreads();
    if (tid == 0) {
        float m = fminf(fminf(red[0], red[1]), fminf(red[2], red[3]));
        atomicMin(min_bits, __builtin_bit_cast(unsigned, m));
    }
}

// ---------------- Kernel 3: e = exp(min_s - s), partial sums -----------------
__global__ __launch_bounds__(256)
void exp_kernel(float* __restrict__ att, const float* __restrict__ ws,
                float* __restrict__ sum) {
    int i = blockIdx.x * blockDim.x + threadIdx.x;   // float4 index
    float m = ws[1];                                  // min_s (stored as bits of positive float)
    float lsum = 0.f;
    if (i < N_CAND / 4) {
        floatx4 s = *(floatx4*)(att + (size_t)i * 4);
        floatx4 e;
#pragma unroll
        for (int k = 0; k < 4; ++k) { e[k] = __expf(m - s[k]); lsum += e[k]; }
        *(floatx4*)(att + (size_t)i * 4) = e;
    }
#pragma unroll
    for (int mm = 1; mm < 64; mm <<= 1) lsum += __shfl_xor(lsum, mm);
    __shared__ float red[4];
    int wid = threadIdx.x >> 6;
    if ((threadIdx.x & 63) == 0) red[wid] = lsum;
    __syncthreads();
    if (threadIdx.x == 0)
        atomicAdd(sum, red[0] + red[1] + red[2] + red[3]);
}

// ---------------- Kernel 4: normalize ---------------------------------------
__global__ __launch_bounds__(256)
void norm_kernel(float* __restrict__ att, const float* __restrict__ ws) {
    int i = blockIdx.x * blockDim.x + threadIdx.x;
    if (i < N_CAND / 4) {
        float inv = 1.0f / ws[2];
        floatx4 v = *(floatx4*)(att + (size_t)i * 4);
#pragma unroll
        for (int k = 0; k < 4; ++k) v[k] *= inv;
        *(floatx4*)(att + (size_t)i * 4) = v;
    }
}

extern "C" void kernel_launch(void* const* d_in, const int* in_sizes, int n_in,
                              void* d_out, int out_size, void* d_ws, size_t ws_size,
                              hipStream_t stream) {
    const float* qz   = (const float*)d_in[0];
    const float* cand = (const float*)d_in[1];
    const float* ctr  = (const float*)d_in[2];
    const float* mus  = (const float*)d_in[3];
    float* out = (float*)d_out;
    float* ws  = (float*)d_ws;

    query_kernel<<<1, 256, 0, stream>>>(qz, ctr, mus, out, ws);
    pot_kernel<<<1024, 256, 0, stream>>>(cand, ctr, mus, ws, out + 64,
                                         ((unsigned*)ws) + 1);
    int blocks34 = (N_CAND / 4 + 255) / 256;   // 489
    exp_kernel<<<blocks34, 256, 0, stream>>>(out + 64, ws, ws + 2);
    norm_kernel<<<blocks34, 256, 0, stream>>>(out + 64, ws);
}

// Round 2
// 60.726 us; speedup vs baseline: 1.2184x; 1.2184x over previous
//
#include <hip/hip_runtime.h>
#include <hip/hip_bf16.h>

#define N_CAND     500000
#define N_TILES    31250      // N_CAND / 16
#define EPS        1e-6f
#define INV_TEMP   10.0f
#define DT_STEP    0.1f
#define POT_BLOCKS 1024

typedef __attribute__((ext_vector_type(8))) short  short8;
typedef __attribute__((ext_vector_type(4))) float  floatx4;

__device__ inline short f32_to_bf16_rne(float f) {
    unsigned u = __builtin_bit_cast(unsigned, f);
    u += 0x7FFFu + ((u >> 16) & 1u);
    return (short)(u >> 16);
}

// Load 8 consecutive floats at p, convert to bf16x8, accumulate sum of squares (f32).
__device__ inline void cvt8(const float* __restrict__ p, short8& b, float& ss) {
    floatx4 v0 = *(const floatx4*)p;
    floatx4 v1 = *(const floatx4*)(p + 4);
#pragma unroll
    for (int k = 0; k < 4; ++k) {
        ss = fmaf(v0[k], v0[k], ss);
        ss = fmaf(v1[k], v1[k], ss);
        b[k]     = f32_to_bf16_rne(v0[k]);
        b[k + 4] = f32_to_bf16_rne(v1[k]);
    }
}

// ---- Mega kernel: q_pot (per block) + query flow (block 0) + c_pot via MFMA
//      + e = exp(-|q_pot - c_pot|/T) + per-block partial sums ----
__global__ __launch_bounds__(256)
void pot_kernel(const float* __restrict__ qz, const float* __restrict__ cand,
                const float* __restrict__ centers, const float* __restrict__ mus,
                float* __restrict__ out, float* __restrict__ partials) {
    int tid = threadIdx.x, wid = tid >> 6, lane = tid & 63;

    // ---- phase 0: cooperative q_pot (every block, ~400 cyc) ----
    __shared__ float qred[4];
    __shared__ float sred[4];
    __shared__ float wj[128];
    {
        int j = tid >> 1;            // center 0..127
        int h = tid & 1;             // half of the 64 dims
        const float* crow = centers + j * 64 + h * 32;
        const float* qrow = qz + h * 32;
        float ssd = 0.f;
#pragma unroll
        for (int k = 0; k < 8; ++k) {
            floatx4 c4 = *(const floatx4*)(crow + k * 4);
            floatx4 q4 = *(const floatx4*)(qrow + k * 4);
#pragma unroll
            for (int x = 0; x < 4; ++x) { float df = c4[x] - q4[x]; ssd = fmaf(df, df, ssd); }
        }
        ssd += __shfl_xor(ssd, 1);   // pair (j,h=0)+(j,h=1) -> full ||q-c_j||^2
        float r = __builtin_amdgcn_sqrtf(fmaxf(ssd, 1e-12f));
        float mu_j = mus[j];
        float potj = (h == 0) ? mu_j * __builtin_amdgcn_rcpf(r + EPS) : 0.f;
        if (blockIdx.x == 0 && h == 0)
            wj[j] = mu_j * __builtin_amdgcn_rcpf(r * r * r + EPS);
#pragma unroll
        for (int m = 1; m < 64; m <<= 1) potj += __shfl_xor(potj, m);
        if (lane == 0) qred[wid] = potj;
    }
    __syncthreads();
    float q_pot = qred[0] + qred[1] + qred[2] + qred[3];

    // ---- block 0 / first wave: query_output flow step ----
    if (blockIdx.x == 0 && tid < 64) {
        float qd = qz[tid];
        float acc = 0.f;
        for (int jj = 0; jj < 128; ++jj)
            acc = fmaf(wj[jj], centers[jj * 64 + tid] - qd, acc);
        out[tid] = fmaf(DT_STEP, acc, qd);
    }

    // ---- B fragments (centers as bf16) + norms + mus in registers ----
    int lr = lane & 15;       // A-row / B-col within 16
    int lg = lane >> 4;       // k-chunk group 0..3
    short8 bfrag[8][2];
    float nc[8], mu[8];
#pragma unroll
    for (int ct = 0; ct < 8; ++ct) {
        int j = ct * 16 + lr;
        float ncp = 0.f;
#pragma unroll
        for (int ks = 0; ks < 2; ++ks)
            cvt8(centers + j * 64 + ks * 32 + lg * 8, bfrag[ct][ks], ncp);
        ncp += __shfl_xor(ncp, 16);
        ncp += __shfl_xor(ncp, 32);
        nc[ct] = ncp;
        mu[ct] = mus[j];
    }

    // ---- main tile loop ----
    float lsum = 0.f;
    for (int t = blockIdx.x * 4 + wid; t < N_TILES; t += POT_BLOCKS * 4) {
        int r0 = t * 16;
        short8 afrag[2];
        float nzp = 0.f;
#pragma unroll
        for (int ks = 0; ks < 2; ++ks)
            cvt8(cand + (size_t)(r0 + lr) * 64 + ks * 32 + lg * 8, afrag[ks], nzp);
        nzp += __shfl_xor(nzp, 16);
        nzp += __shfl_xor(nzp, 32);
        float nzv[4];
#pragma unroll
        for (int v = 0; v < 4; ++v) nzv[v] = __shfl(nzp, lg * 4 + v);

        float pot[4] = {0.f, 0.f, 0.f, 0.f};
#pragma unroll
        for (int ct = 0; ct < 8; ++ct) {
            floatx4 acc = {0.f, 0.f, 0.f, 0.f};
            acc = __builtin_amdgcn_mfma_f32_16x16x32_bf16(afrag[0], bfrag[ct][0], acc, 0, 0, 0);
            acc = __builtin_amdgcn_mfma_f32_16x16x32_bf16(afrag[1], bfrag[ct][1], acc, 0, 0, 0);
#pragma unroll
            for (int v = 0; v < 4; ++v) {
                float d2 = fmaxf(nzv[v] + nc[ct] - 2.f * acc[v], 1e-12f);
                float d = __builtin_amdgcn_sqrtf(d2);
                pot[v] += mu[ct] * __builtin_amdgcn_rcpf(d + EPS);
            }
        }
        float e[4];
#pragma unroll
        for (int v = 0; v < 4; ++v) {
            float p = pot[v];
            p += __shfl_xor(p, 1);
            p += __shfl_xor(p, 2);
            p += __shfl_xor(p, 4);
            p += __shfl_xor(p, 8);          // sum over 16 col-lanes
            float s = fabsf(q_pot - p) * INV_TEMP;
            e[v] = __expf(-s);              // logits <= 0: no max-shift needed
            lsum += (lr == 0) ? e[v] : 0.f;
        }
        if (lr == 0) {
            floatx4 ev = {e[0], e[1], e[2], e[3]};
            *(floatx4*)(out + 64 + r0 + lg * 4) = ev;
        }
    }

    // ---- block partial sum -> plain store (no reset needed) ----
#pragma unroll
    for (int m = 1; m < 64; m <<= 1) lsum += __shfl_xor(lsum, m);
    if (lane == 0) sred[wid] = lsum;
    __syncthreads();
    if (tid == 0) partials[blockIdx.x] = sred[0] + sred[1] + sred[2] + sred[3];
}

// ---- Normalize: re-reduce 1024 partials per block (L2-broadcast), scale ----
__global__ __launch_bounds__(256)
void norm_kernel(float* __restrict__ att, const float* __restrict__ partials) {
    int tid = threadIdx.x;
    float p = partials[tid] + partials[tid + 256] + partials[tid + 512] + partials[tid + 768];
#pragma unroll
    for (int m = 1; m < 64; m <<= 1) p += __shfl_xor(p, m);
    __shared__ float red[4];
    if ((tid & 63) == 0) red[tid >> 6] = p;
    __syncthreads();
    float inv = 1.0f / (red[0] + red[1] + red[2] + red[3]);
    int i = blockIdx.x * 256 + tid;
    if (i < N_CAND / 4) {
        floatx4 v = *(floatx4*)(att + (size_t)i * 4);
#pragma unroll
        for (int k = 0; k < 4; ++k) v[k] *= inv;
        *(floatx4*)(att + (size_t)i * 4) = v;
    }
}

extern "C" void kernel_launch(void* const* d_in, const int* in_sizes, int n_in,
                              void* d_out, int out_size, void* d_ws, size_t ws_size,
                              hipStream_t stream) {
    const float* qz   = (const float*)d_in[0];
    const float* cand = (const float*)d_in[1];
    const float* ctr  = (const float*)d_in[2];
    const float* mus  = (const float*)d_in[3];
    float* out = (float*)d_out;
    float* ws  = (float*)d_ws;

    pot_kernel<<<POT_BLOCKS, 256, 0, stream>>>(qz, cand, ctr, mus, out, ws + 256);
    int blocks2 = (N_CAND / 4 + 255) / 256;   // 489
    norm_kernel<<<blocks2, 256, 0, stream>>>(out + 64, ws + 256);
}

// Round 3
// 58.829 us; speedup vs baseline: 1.2577x; 1.0323x over previous
//
#include <hip/hip_runtime.h>
#include <hip/hip_bf16.h>

#define N_CAND     500000
#define N_GROUPS   7813        // ceil(500000 / 64) groups of 64 rows
#define EPS        1e-6f
#define INV_TEMP   10.0f
#define DT_STEP    0.1f
#define POT_BLOCKS 1024

typedef __attribute__((ext_vector_type(8))) short  short8;
typedef __attribute__((ext_vector_type(4))) float  floatx4;

__device__ inline short f32_to_bf16_rne(float f) {
    unsigned u = __builtin_bit_cast(unsigned, f);
    u += 0x7FFFu + ((u >> 16) & 1u);
    return (short)(u >> 16);
}

__device__ inline void gload_lds16(const float* g, void* l) {
    __builtin_amdgcn_global_load_lds(
        (const __attribute__((address_space(1))) void*)g,
        (__attribute__((address_space(3))) void*)l,
        16, 0, 0);
}

// ---- Mega kernel: q_pot + query flow (block 0) + c_pot via MFMA over
//      LDS-staged (swizzled) candidate tiles + exp + per-block partial sums ----
__global__ __launch_bounds__(256)
void pot_kernel(const float* __restrict__ qz, const float* __restrict__ cand,
                const float* __restrict__ centers, const float* __restrict__ mus,
                float* __restrict__ out, float* __restrict__ partials) {
    __shared__ __align__(16) char smem[32768];   // 2 x (64 rows x 256 B)
    __shared__ float qred[4];
    __shared__ float sred[4];
    __shared__ float wj[128];

    int tid = threadIdx.x, wid = tid >> 6, lane = tid & 63;
    int lr = lane & 15;       // A-row / B-col within 16
    int lg = lane >> 4;       // k-chunk group 0..3

    // ---- staging address precompute (per lane, loop-invariant) ----
    // stage instr i of wave wid covers LDS granules G = wid*256 + i*64 + lane
    // (granule = 16 B). row = G>>4, c' = G&15 = lane&15. Source granule
    // c = c' ^ (row&7)  (XOR involution; read side applies the same XOR).
    int rowl[4], coff[4];
#pragma unroll
    for (int i = 0; i < 4; ++i) {
        rowl[i] = wid * 16 + i * 4 + (lane >> 4);
        coff[i] = ((lane & 15) ^ (rowl[i] & 7)) * 4;   // float offset of granule
    }
    // swizzled ds_read_b128 byte offsets: granule c = ks*8 + lg*2 + h of row lr
    int roff[2][2];
#pragma unroll
    for (int ks = 0; ks < 2; ++ks)
#pragma unroll
        for (int h = 0; h < 2; ++h)
            roff[ks][h] = wid * 4096 + lr * 256 + ((ks * 8 + lg * 2 + h) ^ (lr & 7)) * 16;

    // ---- prologue stage of first group (async; hides under phase 0) ----
    int g0 = blockIdx.x;
    {
        const int gg = g0;
#pragma unroll
        for (int i = 0; i < 4; ++i) {
            int grow = gg * 64 + rowl[i];
            grow = grow < N_CAND ? grow : N_CAND - 1;
            gload_lds16(cand + (size_t)grow * 64 + coff[i],
                        smem + wid * 4096 + i * 1024);
        }
    }

    // ---- phase 0: cooperative q_pot (every block) ----
    {
        int j = tid >> 1;            // center 0..127
        int h = tid & 1;             // half of the 64 dims
        const float* crow = centers + j * 64 + h * 32;
        const float* qrow = qz + h * 32;
        float ssd = 0.f;
#pragma unroll
        for (int k = 0; k < 8; ++k) {
            floatx4 c4 = *(const floatx4*)(crow + k * 4);
            floatx4 q4 = *(const floatx4*)(qrow + k * 4);
#pragma unroll
            for (int x = 0; x < 4; ++x) { float df = c4[x] - q4[x]; ssd = fmaf(df, df, ssd); }
        }
        ssd += __shfl_xor(ssd, 1);   // full ||q-c_j||^2
        float rs = __builtin_amdgcn_rsqf(fmaxf(ssd, 1e-12f));
        float mu_j = mus[j];
        float potj = (h == 0) ? mu_j * rs : 0.f;
        if (blockIdx.x == 0 && h == 0)
            wj[j] = mu_j * rs * rs * rs;
#pragma unroll
        for (int m = 1; m < 64; m <<= 1) potj += __shfl_xor(potj, m);
        if (lane == 0) qred[wid] = potj;
    }
    __syncthreads();
    float q_pot = qred[0] + qred[1] + qred[2] + qred[3];

    // ---- block 0 / first wave: query_output flow step ----
    if (blockIdx.x == 0 && tid < 64) {
        float qd = qz[tid];
        float acc = 0.f;
        for (int jj = 0; jj < 128; ++jj)
            acc = fmaf(wj[jj], centers[jj * 64 + tid] - qd, acc);
        out[tid] = fmaf(DT_STEP, acc, qd);
    }

    // ---- B fragments (centers as bf16) + norms + mus in registers ----
    short8 bfrag[8][2];
    float nc[8], mu[8];
#pragma unroll
    for (int ct = 0; ct < 8; ++ct) {
        int j = ct * 16 + lr;
        float ncp = 0.f;
#pragma unroll
        for (int ks = 0; ks < 2; ++ks) {
            const float* p = centers + j * 64 + ks * 32 + lg * 8;
            floatx4 v0 = *(const floatx4*)p;
            floatx4 v1 = *(const floatx4*)(p + 4);
            short8 b;
#pragma unroll
            for (int k = 0; k < 4; ++k) {
                ncp = fmaf(v0[k], v0[k], ncp);
                ncp = fmaf(v1[k], v1[k], ncp);
                b[k]     = f32_to_bf16_rne(v0[k]);
                b[k + 4] = f32_to_bf16_rne(v1[k]);
            }
            bfrag[ct][ks] = b;
        }
        ncp += __shfl_xor(ncp, 16);
        ncp += __shfl_xor(ncp, 32);
        nc[ct] = ncp;
        mu[ct] = mus[j];
    }

    // ---- main double-buffered loop over 64-row groups ----
    float lsum = 0.f;
    int cur = 0;
    for (int g = g0; g < N_GROUPS; g += POT_BLOCKS) {
        __syncthreads();                 // buf[cur] staged (vmcnt drained) + consumers done
        int gn = g + POT_BLOCKS;
        if (gn < N_GROUPS) {             // prefetch next group into buf[cur^1]
            char* lbase = smem + (cur ^ 1) * 16384 + wid * 4096;
#pragma unroll
            for (int i = 0; i < 4; ++i) {
                int grow = gn * 64 + rowl[i];
                grow = grow < N_CAND ? grow : N_CAND - 1;
                gload_lds16(cand + (size_t)grow * 64 + coff[i], lbase + i * 1024);
            }
        }

        // ---- compute wave's 16-row subtile from buf[cur] ----
        const char* buf = smem + cur * 16384;
        short8 afrag[2];
        float nzp = 0.f;
#pragma unroll
        for (int ks = 0; ks < 2; ++ks) {
            floatx4 v0 = *(const floatx4*)(buf + roff[ks][0]);
            floatx4 v1 = *(const floatx4*)(buf + roff[ks][1]);
            short8 b;
#pragma unroll
            for (int k = 0; k < 4; ++k) {
                nzp = fmaf(v0[k], v0[k], nzp);
                nzp = fmaf(v1[k], v1[k], nzp);
                b[k]     = f32_to_bf16_rne(v0[k]);
                b[k + 4] = f32_to_bf16_rne(v1[k]);
            }
            afrag[ks] = b;
        }
        nzp += __shfl_xor(nzp, 16);
        nzp += __shfl_xor(nzp, 32);      // ||z_row lr||^2 on all lanes
        float nzv[4];
#pragma unroll
        for (int v = 0; v < 4; ++v) nzv[v] = __shfl(nzp, lg * 4 + v);

        float pot[4] = {0.f, 0.f, 0.f, 0.f};
#pragma unroll
        for (int ct = 0; ct < 8; ++ct) {
            floatx4 acc = {0.f, 0.f, 0.f, 0.f};
            acc = __builtin_amdgcn_mfma_f32_16x16x32_bf16(afrag[0], bfrag[ct][0], acc, 0, 0, 0);
            acc = __builtin_amdgcn_mfma_f32_16x16x32_bf16(afrag[1], bfrag[ct][1], acc, 0, 0, 0);
#pragma unroll
            for (int v = 0; v < 4; ++v) {
                float d2 = fmaxf(nzv[v] + nc[ct] - 2.f * acc[v], 1e-12f);
                pot[v] += mu[ct] * __builtin_amdgcn_rsqf(d2);   // 1/(d+eps) ~ rsqrt(d2)
            }
        }

        bool valid = (g * 64 + wid * 16) < N_CAND;   // N_CAND%64==32: whole-wave granularity
        float e[4];
#pragma unroll
        for (int v = 0; v < 4; ++v) {
            float p = pot[v];
            p += __shfl_xor(p, 1);
            p += __shfl_xor(p, 2);
            p += __shfl_xor(p, 4);
            p += __shfl_xor(p, 8);          // sum over 16 col-lanes
            float s = fabsf(q_pot - p) * INV_TEMP;
            e[v] = __expf(-s);              // logits <= 0: no max-shift needed
            if (valid && lr == 0) lsum += e[v];
        }
        if (valid && lr == 0) {
            int r0 = g * 64 + wid * 16;
            floatx4 ev = {e[0], e[1], e[2], e[3]};
            *(floatx4*)(out + 64 + r0 + lg * 4) = ev;
        }
        cur ^= 1;
    }

    // ---- block partial sum -> plain store (no reset needed) ----
#pragma unroll
    for (int m = 1; m < 64; m <<= 1) lsum += __shfl_xor(lsum, m);
    if (lane == 0) sred[wid] = lsum;
    __syncthreads();
    if (tid == 0) partials[blockIdx.x] = sred[0] + sred[1] + sred[2] + sred[3];
}

// ---- Normalize: re-reduce 1024 partials per block (L2-broadcast), scale ----
__global__ __launch_bounds__(256)
void norm_kernel(float* __restrict__ att, const float* __restrict__ partials) {
    int tid = threadIdx.x;
    float p = partials[tid] + partials[tid + 256] + partials[tid + 512] + partials[tid + 768];
#pragma unroll
    for (int m = 1; m < 64; m <<= 1) p += __shfl_xor(p, m);
    __shared__ float red[4];
    if ((tid & 63) == 0) red[tid >> 6] = p;
    __syncthreads();
    float inv = 1.0f / (red[0] + red[1] + red[2] + red[3]);
    int i = blockIdx.x * 256 + tid;
    if (i < N_CAND / 4) {
        floatx4 v = *(floatx4*)(att + (size_t)i * 4);
#pragma unroll
        for (int k = 0; k < 4; ++k) v[k] *= inv;
        *(floatx4*)(att + (size_t)i * 4) = v;
    }
}

extern "C" void kernel_launch(void* const* d_in, const int* in_sizes, int n_in,
                              void* d_out, int out_size, void* d_ws, size_t ws_size,
                              hipStream_t stream) {
    const float* qz   = (const float*)d_in[0];
    const float* cand = (const float*)d_in[1];
    const float* ctr  = (const float*)d_in[2];
    const float* mus  = (const float*)d_in[3];
    float* out = (float*)d_out;
    float* ws  = (float*)d_ws;

    pot_kernel<<<POT_BLOCKS, 256, 0, stream>>>(qz, cand, ctr, mus, out, ws + 256);
    int blocks2 = (N_CAND / 4 + 255) / 256;   // 489
    norm_kernel<<<blocks2, 256, 0, stream>>>(out + 64, ws + 256);
}

// Round 4
// 42.581 us; speedup vs baseline: 1.7376x; 1.3816x over previous
//
#include <hip/hip_runtime.h>
#include <hip/hip_bf16.h>

#define N_CAND     500000
#define N_PAIRS    15625       // N_CAND / 32 (exact)
#define INV_TEMP   10.0f
#define DT_STEP    0.1f
#define POT_BLOCKS 1024

typedef __attribute__((ext_vector_type(8))) short  short8;
typedef __attribute__((ext_vector_type(4))) float  floatx4;

__device__ inline short f32_to_bf16_rne(float f) {
    unsigned u = __builtin_bit_cast(unsigned, f);
    u += 0x7FFFu + ((u >> 16) & 1u);
    return (short)(u >> 16);
}

// Load 16 floats (two floatx4 pairs) -> bf16x8, accumulate sum of squares.
__device__ inline void cvt8v(floatx4 v0, floatx4 v1, short8& b, float& ss) {
#pragma unroll
    for (int k = 0; k < 4; ++k) {
        ss = fmaf(v0[k], v0[k], ss);
        ss = fmaf(v1[k], v1[k], ss);
        b[k]     = f32_to_bf16_rne(v0[k]);
        b[k + 4] = f32_to_bf16_rne(v1[k]);
    }
}

// ---- Mega kernel: q_pot + query flow (block 0) + c_pot via swapped-operand
//      MFMA (centers=A in LDS, candidates=B per-lane) + exp + partial sums ----
__global__ __launch_bounds__(256)
void pot_kernel(const float* __restrict__ qz, const float* __restrict__ cand,
                const float* __restrict__ centers, const float* __restrict__ mus,
                float* __restrict__ out, float* __restrict__ partials) {
    __shared__ __align__(16) short8  cfrag[8][2][64];  // 16 KB center A-fragments
    __shared__ __align__(16) floatx4 ncin[8][4];       // -||c||^2/2 per (ct, row-group)
    __shared__ __align__(16) floatx4 muv8[8][4];       // mu per (ct, row-group)
    __shared__ float qred[4], sred[4], wj[128];

    int tid = threadIdx.x, wid = tid >> 6, lane = tid & 63;
    int lr = lane & 15;       // fragment index (candidate col / center row)
    int lg = lane >> 4;       // k-chunk group 0..3

    // ---- phase 0a: cooperative q_pot (every block) ----
    {
        int j = tid >> 1;            // center 0..127
        int h = tid & 1;             // half of the 64 dims
        const float* crow = centers + j * 64 + h * 32;
        const float* qrow = qz + h * 32;
        float ssd = 0.f;
#pragma unroll
        for (int k = 0; k < 8; ++k) {
            floatx4 c4 = *(const floatx4*)(crow + k * 4);
            floatx4 q4 = *(const floatx4*)(qrow + k * 4);
#pragma unroll
            for (int x = 0; x < 4; ++x) { float df = c4[x] - q4[x]; ssd = fmaf(df, df, ssd); }
        }
        ssd += __shfl_xor(ssd, 1);   // full ||q-c_j||^2
        float rs = __builtin_amdgcn_rsqf(fmaxf(ssd, 1e-12f));
        float mu_j = mus[j];
        float potj = (h == 0) ? mu_j * rs : 0.f;
        if (blockIdx.x == 0 && h == 0)
            wj[j] = mu_j * rs * rs * rs;
#pragma unroll
        for (int m = 1; m < 64; m <<= 1) potj += __shfl_xor(potj, m);
        if (lane == 0) qred[wid] = potj;
    }

    // ---- phase 0b: center fragments + (-nc/2) + mu into LDS ----
#pragma unroll
    for (int c2 = 0; c2 < 2; ++c2) {
        int ct = wid * 2 + c2;
        int j = ct * 16 + lr;
        const float* p = centers + j * 64 + lg * 8;
        float ncp = 0.f;
        short8 b0, b1;
        cvt8v(*(const floatx4*)p,        *(const floatx4*)(p + 4),  b0, ncp);
        cvt8v(*(const floatx4*)(p + 32), *(const floatx4*)(p + 36), b1, ncp);
        cfrag[ct][0][lane] = b0;
        cfrag[ct][1][lane] = b1;
        ncp += __shfl_xor(ncp, 16);
        ncp += __shfl_xor(ncp, 32);                    // full ||c_j||^2
        if (lg == 0) ((float*)ncin)[ct * 16 + lr] = -0.5f * ncp;
        if (lg == 1) ((float*)muv8)[ct * 16 + lr] = mus[j];
    }
    __syncthreads();
    float q_pot = qred[0] + qred[1] + qred[2] + qred[3];

    // ---- block 0 / first wave: query_output flow step ----
    if (blockIdx.x == 0 && tid < 64) {
        float qd = qz[tid];
        float acc = 0.f;
        for (int jj = 0; jj < 128; ++jj)
            acc = fmaf(wj[jj], centers[jj * 64 + tid] - qd, acc);
        out[tid] = fmaf(DT_STEP, acc, qd);
    }

    // ---- main loop: 2 tiles (32 candidates) per wave-iteration, no barriers ----
    float lsum = 0.f;
    const float* baseA = cand + (size_t)lr * 64 + lg * 8;
    for (int p = blockIdx.x * 4 + wid; p < N_PAIRS; p += POT_BLOCKS * 4) {
        size_t r0 = (size_t)p * 32;
        const float* pa = baseA + r0 * 64;
        const float* pb = pa + 16 * 64;
        floatx4 a0 = *(const floatx4*)pa;
        floatx4 a1 = *(const floatx4*)(pa + 4);
        floatx4 a2 = *(const floatx4*)(pa + 32);
        floatx4 a3 = *(const floatx4*)(pa + 36);
        floatx4 c0 = *(const floatx4*)pb;
        floatx4 c1 = *(const floatx4*)(pb + 4);
        floatx4 c2 = *(const floatx4*)(pb + 32);
        floatx4 c3 = *(const floatx4*)(pb + 36);

        short8 afA[2], afB[2];
        float nzA = 0.f, nzB = 0.f;
        cvt8v(a0, a1, afA[0], nzA);
        cvt8v(a2, a3, afA[1], nzA);
        cvt8v(c0, c1, afB[0], nzB);
        cvt8v(c2, c3, afB[1], nzB);
        nzA += __shfl_xor(nzA, 16);
        nzA += __shfl_xor(nzA, 32);   // every lane: full ||z_c||^2 of its cand c=lr
        nzB += __shfl_xor(nzB, 16);
        nzB += __shfl_xor(nzB, 32);

        float potA = 0.f, potB = 0.f;
#pragma unroll
        for (int ct = 0; ct < 8; ++ct) {
            floatx4 nci = ncin[ct][lg];
            floatx4 m4  = muv8[ct][lg];
            short8 f0 = cfrag[ct][0][lane];
            short8 f1 = cfrag[ct][1][lane];
            floatx4 aA = __builtin_amdgcn_mfma_f32_16x16x32_bf16(f0, afA[0], nci, 0, 0, 0);
            aA         = __builtin_amdgcn_mfma_f32_16x16x32_bf16(f1, afA[1], aA,  0, 0, 0);
            floatx4 aB = __builtin_amdgcn_mfma_f32_16x16x32_bf16(f0, afB[0], nci, 0, 0, 0);
            aB         = __builtin_amdgcn_mfma_f32_16x16x32_bf16(f1, afB[1], aB,  0, 0, 0);
#pragma unroll
            for (int r = 0; r < 4; ++r) {
                // aX[r] = dot - nc/2 for center m = ct*16 + lg*4 + r, cand = lr
                float d2A = fmaxf(fmaf(-2.f, aA[r], nzA), 1e-12f);
                potA = fmaf(m4[r], __builtin_amdgcn_rsqf(d2A), potA);
                float d2B = fmaxf(fmaf(-2.f, aB[r], nzB), 1e-12f);
                potB = fmaf(m4[r], __builtin_amdgcn_rsqf(d2B), potB);
            }
        }
        potA += __shfl_xor(potA, 16);
        potA += __shfl_xor(potA, 32);  // sum the 4 disjoint center-groups
        potB += __shfl_xor(potB, 16);
        potB += __shfl_xor(potB, 32);

        if (lg == 0) {
            float eA = __expf(-fabsf(q_pot - potA) * INV_TEMP);
            float eB = __expf(-fabsf(q_pot - potB) * INV_TEMP);
            out[64 + r0 + lr]      = eA;   // 16 consecutive floats per wave
            out[64 + r0 + 16 + lr] = eB;
            lsum += eA + eB;
        }
    }

    // ---- block partial sum -> plain store (no reset needed) ----
#pragma unroll
    for (int m = 1; m < 64; m <<= 1) lsum += __shfl_xor(lsum, m);
    if (lane == 0) sred[wid] = lsum;
    __syncthreads();
    if (tid == 0) partials[blockIdx.x] = sred[0] + sred[1] + sred[2] + sred[3];
}

// ---- Normalize: re-reduce 1024 partials per block (L2-broadcast), scale ----
__global__ __launch_bounds__(256)
void norm_kernel(float* __restrict__ att, const float* __restrict__ partials) {
    int tid = threadIdx.x;
    float p = partials[tid] + partials[tid + 256] + partials[tid + 512] + partials[tid + 768];
#pragma unroll
    for (int m = 1; m < 64; m <<= 1) p += __shfl_xor(p, m);
    __shared__ float red[4];
    if ((tid & 63) == 0) red[tid >> 6] = p;
    __syncthreads();
    float inv = 1.0f / (red[0] + red[1] + red[2] + red[3]);
    int i = blockIdx.x * 256 + tid;
    if (i < N_CAND / 4) {
        floatx4 v = *(floatx4*)(att + (size_t)i * 4);
#pragma unroll
        for (int k = 0; k < 4; ++k) v[k] *= inv;
        *(floatx4*)(att + (size_t)i * 4) = v;
    }
}

extern "C" void kernel_launch(void* const* d_in, const int* in_sizes, int n_in,
                              void* d_out, int out_size, void* d_ws, size_t ws_size,
                              hipStream_t stream) {
    const float* qz   = (const float*)d_in[0];
    const float* cand = (const float*)d_in[1];
    const float* ctr  = (const float*)d_in[2];
    const float* mus  = (const float*)d_in[3];
    float* out = (float*)d_out;
    float* ws  = (float*)d_ws;

    pot_kernel<<<POT_BLOCKS, 256, 0, stream>>>(qz, cand, ctr, mus, out, ws + 256);
    int blocks2 = (N_CAND / 4 + 255) / 256;   // 489
    norm_kernel<<<blocks2, 256, 0, stream>>>(out + 64, ws + 256);
}